// Round 1
// baseline (639.589 us; speedup 1.0000x reference)
//
#include <hip/hip_runtime.h>
#include <hip/hip_bf16.h>
#include <cstdint>

#define B_   16
#define N_   1369
#define NP   1408
#define D_   1024

typedef __bf16 bf16x8_t __attribute__((ext_vector_type(8)));
typedef __bf16 bf16x4_t __attribute__((ext_vector_type(4)));
typedef float  f32x4_t  __attribute__((ext_vector_type(4)));

__device__ __forceinline__ float  bf2f(__bf16 x) { return (float)x; }
__device__ __forceinline__ __bf16 f2bf(float x)  { return (__bf16)x; }

#define GLOAD_LDS16(g, l) __builtin_amdgcn_global_load_lds( \
    (const __attribute__((address_space(1))) void*)(g),     \
    (__attribute__((address_space(3))) void*)(l), 16, 0, 0)

// ---------------------------------------------------------------- pos table
__global__ __launch_bounds__(256)
void pos_kernel(float* __restrict__ pos)
{
    const int idx = blockIdx.x * 256 + threadIdx.x;
    if (idx >= N_ * D_) return;
    const int n = idx >> 10, f = idx & 1023;
    const int row = n / 37, col = n - row * 37;
    const float base = (f < 512) ? (float)row : (float)col;
    const int  t2   = (f & 511) >> 1;
    // div[t] = exp(-(2t)*ln(10000)/512) = exp(-t*0.035977892078032)
    const float dv  = __expf(-0.03597789207803197f * (float)t2);
    const float ang = base * dv;
    pos[idx] = (f & 1) ? cosf(ang) : sinf(ang);
}

// ----------------------------------------------- x = patch + pos, cast bf16
__global__ __launch_bounds__(256)
void addpos_kernel(const float* __restrict__ patch, const float* __restrict__ pos,
                   __bf16* __restrict__ X)
{
    const long tid = (long)blockIdx.x * 256 + threadIdx.x;
    const long e   = tid * 4;                 // element index in [B,NP,D]
    const int  f   = (int)(e & 1023);
    const long nb  = e >> 10;                 // b*NP + n
    const int  n   = (int)(nb % NP);
    const long b   = nb / NP;
    bf16x4_t o;
    if (n < N_) {
        const float4 p = *(const float4*)(patch + ((b * N_ + n) << 10) + f);
        const float4 q = *(const float4*)(pos + ((long)n << 10) + f);
        o[0] = f2bf(p.x + q.x); o[1] = f2bf(p.y + q.y);
        o[2] = f2bf(p.z + q.z); o[3] = f2bf(p.w + q.w);
    } else {
        o[0] = o[1] = o[2] = o[3] = f2bf(0.f);  // zero pad rows
    }
    *(bf16x4_t*)(X + e) = o;
}

// ------------------------------------ W[i][o] -> WT[o][i] bf16 (3 matrices)
__global__ __launch_bounds__(256)
void wcast_kernel(const float* __restrict__ W0, const float* __restrict__ W1,
                  const float* __restrict__ W2,
                  __bf16* __restrict__ T0, __bf16* __restrict__ T1, __bf16* __restrict__ T2)
{
    const float* W = blockIdx.z == 0 ? W0 : (blockIdx.z == 1 ? W1 : W2);
    __bf16*      T = blockIdx.z == 0 ? T0 : (blockIdx.z == 1 ? T1 : T2);
    __shared__ float tile[64][65];
    const int o0 = blockIdx.x * 64, i0 = blockIdx.y * 64;
    const int t = threadIdx.x;
    const int tr = t >> 4, tc = (t & 15) * 4;
    #pragma unroll
    for (int rr = 0; rr < 64; rr += 16) {
        float4 v = *(const float4*)(W + (long)(i0 + rr + tr) * 1024 + o0 + tc);
        tile[rr + tr][tc + 0] = v.x; tile[rr + tr][tc + 1] = v.y;
        tile[rr + tr][tc + 2] = v.z; tile[rr + tr][tc + 3] = v.w;
    }
    __syncthreads();
    #pragma unroll
    for (int rr = 0; rr < 64; rr += 16) {
        bf16x4_t o;
        o[0] = f2bf(tile[tc + 0][rr + tr]); o[1] = f2bf(tile[tc + 1][rr + tr]);
        o[2] = f2bf(tile[tc + 2][rr + tr]); o[3] = f2bf(tile[tc + 3][rr + tr]);
        *(bf16x4_t*)(T + (long)(o0 + rr + tr) * 1024 + i0 + tc) = o;
    }
}

// --------------------------------------------------------------- GEMM (TN)
// C[m,n] = scale * sum_k A[m,k]*Bt[n,k] (+ bias[n]); A,Bt,C bf16, acc fp32.
// 128x128 tile, BK=32, 4 waves (2x2 of 64x64), 16x16x32 bf16 MFMA,
// global_load_lds width-16 staging (m97 structure).
template<int HAS_BIAS>
__global__ __launch_bounds__(256)
void gemm_tn(const __bf16* __restrict__ A, const __bf16* __restrict__ Bt,
             __bf16* __restrict__ C, const float* __restrict__ bias,
             int M, int Nn, int Kd, float scale,
             long sA, long sB, long sC)
{
    A  += (long)blockIdx.z * sA;
    Bt += (long)blockIdx.z * sB;
    C  += (long)blockIdx.z * sC;
    const int m0 = blockIdx.y * 128;
    const int n0 = blockIdx.x * 128;
    __shared__ __bf16 As[128 * 32];
    __shared__ __bf16 Bs[128 * 32];
    const int t = threadIdx.x;
    const int w = t >> 6, l = t & 63;
    const int wr = w >> 1, wc = w & 1;
    const int lr = l & 15, lh = l >> 4;

    f32x4_t acc[4][4] = {};

    // fragment read bases (lane lr = tile row, lh*8 = k offset)
    const __bf16* aRd = As + (wr * 64 + lr) * 32 + lh * 8;
    const __bf16* bRd = Bs + (wc * 64 + lr) * 32 + lh * 8;

    // staging: linear byte L = c*4096 + w*1024 + l*16 ; row = L/64, eloff = (L%64)/2
    const int L0 = w * 1024 + l * 16;
    const int r0 = L0 >> 6;
    const int e0 = (L0 & 63) >> 1;
    const __bf16* gA0 = A  + (long)(m0 + r0)      * Kd + e0;
    const __bf16* gA1 = A  + (long)(m0 + r0 + 64) * Kd + e0;
    const __bf16* gB0 = Bt + (long)(n0 + r0)      * Kd + e0;
    const __bf16* gB1 = Bt + (long)(n0 + r0 + 64) * Kd + e0;
    __bf16* lA0 = As + w * 512;
    __bf16* lA1 = As + 2048 + w * 512;
    __bf16* lB0 = Bs + w * 512;
    __bf16* lB1 = Bs + 2048 + w * 512;

    for (int k0 = 0; k0 < Kd; k0 += 32) {
        GLOAD_LDS16(gA0 + k0, lA0);
        GLOAD_LDS16(gA1 + k0, lA1);
        GLOAD_LDS16(gB0 + k0, lB0);
        GLOAD_LDS16(gB1 + k0, lB1);
        __syncthreads();   // drains vmcnt -> LDS tiles ready
        bf16x8_t af[4], bfm[4];
        #pragma unroll
        for (int i = 0; i < 4; ++i) af[i]  = *(const bf16x8_t*)(aRd + i * 16 * 32);
        #pragma unroll
        for (int j = 0; j < 4; ++j) bfm[j] = *(const bf16x8_t*)(bRd + j * 16 * 32);
        #pragma unroll
        for (int i = 0; i < 4; ++i)
            #pragma unroll
            for (int j = 0; j < 4; ++j)
                acc[i][j] = __builtin_amdgcn_mfma_f32_16x16x32_bf16(af[i], bfm[j], acc[i][j], 0, 0, 0);
        __syncthreads();   // before next stage overwrites LDS
    }

    // epilogue: C/D layout col=lane&15, row=(lane>>4)*4+reg (m89-verified)
    #pragma unroll
    for (int i = 0; i < 4; ++i) {
        const int row = m0 + wr * 64 + i * 16 + lh * 4;
        #pragma unroll
        for (int j = 0; j < 4; ++j) {
            const int col = n0 + wc * 64 + j * 16 + lr;
            const float bb = HAS_BIAS ? bias[col] : 0.0f;
            #pragma unroll
            for (int q = 0; q < 4; ++q) {
                const float v = acc[i][j][q] * scale + bb;
                C[(long)(row + q) * Nn + col] = f2bf(v);
            }
        }
    }
}

// ------------------------------------------------- row softmax, in place
__global__ __launch_bounds__(256)
void softmax_kernel(__bf16* __restrict__ S)
{
    const int q = blockIdx.x, b = blockIdx.y;
    __bf16* row = S + ((long)b * NP + q) * NP;
    const int t = threadIdx.x;
    float v[6];
    float m = -1e30f;
    #pragma unroll
    for (int i = 0; i < 6; ++i) {
        const int k = t + i * 256;
        float x = -1e30f;
        if (k < N_) x = bf2f(row[k]);
        v[i] = x;
        m = fmaxf(m, x);
    }
    __shared__ float red[8];
    #pragma unroll
    for (int o = 32; o; o >>= 1) m = fmaxf(m, __shfl_xor(m, o));
    if (!(t & 63)) red[t >> 6] = m;
    __syncthreads();
    m = fmaxf(fmaxf(red[0], red[1]), fmaxf(red[2], red[3]));
    float s = 0.f;
    #pragma unroll
    for (int i = 0; i < 6; ++i) {
        const int k = t + i * 256;
        if (k < N_) { const float e = __expf(v[i] - m); v[i] = e; s += e; }
    }
    #pragma unroll
    for (int o = 32; o; o >>= 1) s += __shfl_xor(s, o);
    if (!(t & 63)) red[4 + (t >> 6)] = s;
    __syncthreads();
    s = red[4] + red[5] + red[6] + red[7];
    const float inv = 1.f / s;
    #pragma unroll
    for (int i = 0; i < 6; ++i) {
        const int k = t + i * 256;
        if (k < N_)      row[k] = f2bf(v[i] * inv);
        else if (k < NP) row[k] = f2bf(0.f);
    }
}

// --------------------- weighted column sums over attn (q-chunked + atomic)
template<int WEIGHTED>
__global__ __launch_bounds__(256)
void colsum_kernel(const __bf16* __restrict__ attn, const float* __restrict__ wv,
                   float* __restrict__ out)
{
    const int k = blockIdx.x * 256 + threadIdx.x;
    const int b = blockIdx.y;
    const int q0 = blockIdx.z * 172;
    const int q1 = (q0 + 172 < N_) ? q0 + 172 : N_;
    if (k >= N_) return;
    const __bf16* base = attn + (long)b * NP * NP + k;
    float s = 0.f;
    for (int q = q0; q < q1; ++q) {
        float a = bf2f(base[(long)q * NP]);
        if (WEIGHTED) a *= wv[b * NP + q];
        s += a;
    }
    atomicAdd(out + b * NP + k, s);
}

// ------------------- pa -> normalize -> curiosity modulation -> fa (output)
// NOTE: var(pa) is dominated by the fixed center-bias variance (~5e-3 >> 1e-6),
// so the reference's variance-fallback chain never triggers: branch 1 only.
__global__ __launch_bounds__(256)
void fa_kernel(const float* __restrict__ pa_raw, const float* __restrict__ curiosity,
               const float* __restrict__ Wc1, const float* __restrict__ bc1,
               const float* __restrict__ Wc2, const float* __restrict__ bc2,
               const float* __restrict__ aw_p,
               float* __restrict__ fa_ws, float* __restrict__ out_fa)
{
    const int b = blockIdx.x, t = threadIdx.x;
    __shared__ float hsh[64];
    __shared__ float red[8];
    __shared__ float cwsh;
    if (t < 64) hsh[t] = fmaxf(0.f, curiosity[b] * Wc1[t] + bc1[t]);
    __syncthreads();
    if (t < 8) {
        float a = bc2[t];
        for (int j = 0; j < 64; ++j) a += hsh[j] * Wc2[j * 8 + t];
        red[t] = 1.f / (1.f + __expf(-a));
    }
    __syncthreads();
    if (t == 0) {
        float cw = 0.f;
        for (int i = 0; i < 8; ++i) cw += red[i];
        cwsh = cw * 0.125f;
    }
    __syncthreads();
    const float aw   = aw_p[0];
    const float modf = 1.f + aw * cwsh;
    const float sig  = 37.f / 6.f;
    const float inv2s2 = 1.f / (2.f * sig * sig);
    float pv[6];
    float s1 = 0.f;
    #pragma unroll
    for (int i = 0; i < 6; ++i) {
        const int k = t + i * 256;
        float p = 0.f;
        if (k < N_) {
            const int y = k / 37, x = k - y * 37;
            const float d2 = (float)((x - 18) * (x - 18) + (y - 18) * (y - 18));
            const float cb = 0.3f * __expf(-d2 * inv2s2);
            p = pa_raw[b * NP + k] * (1.f / 1369.f) + cb;
        }
        pv[i] = p; s1 += p;
    }
    #pragma unroll
    for (int o = 32; o; o >>= 1) s1 += __shfl_xor(s1, o);
    __syncthreads();            // red reuse hazard
    if (!(t & 63)) red[t >> 6] = s1;
    __syncthreads();
    s1 = red[0] + red[1] + red[2] + red[3];
    const float inv1 = 1.f / (s1 + 1e-8f);
    float s2 = 0.f;
    #pragma unroll
    for (int i = 0; i < 6; ++i) {
        const int k = t + i * 256;
        if (k < N_) {
            const float f = fmaxf(pv[i] * inv1 * modf, 1e-8f);  // clip(.,1e-8)
            pv[i] = f; s2 += f;
        }
    }
    #pragma unroll
    for (int o = 32; o; o >>= 1) s2 += __shfl_xor(s2, o);
    if (!(t & 63)) red[4 + (t >> 6)] = s2;
    __syncthreads();
    s2 = red[4] + red[5] + red[6] + red[7];
    const float inv2 = 1.f / (s2 + 1e-8f);
    #pragma unroll
    for (int i = 0; i < 6; ++i) {
        const int k = t + i * 256;
        if (k < N_) {
            const float f = pv[i] * inv2;
            fa_ws[b * NP + k]  = f;
            out_fa[b * N_ + k] = f;
        }
    }
}

// ------------------------------------- weighted[b,d] = sum_k g[b,k]*V[b,k,d]
__global__ __launch_bounds__(256)
void weighted_kernel(const float* __restrict__ g, const __bf16* __restrict__ V,
                     float* __restrict__ wout)
{
    const int b  = blockIdx.y;
    const int k0 = blockIdx.x * 86;
    const int k1 = (k0 + 86 < N_) ? k0 + 86 : N_;
    const int d  = threadIdx.x * 4;
    float a0 = 0, a1 = 0, a2 = 0, a3 = 0;
    const __bf16* vb = V + (long)b * NP * D_ + d;
    for (int k = k0; k < k1; ++k) {
        const float gv = g[b * NP + k];
        bf16x4_t vv = *(const bf16x4_t*)(vb + (long)k * D_);
        a0 += gv * bf2f(vv[0]); a1 += gv * bf2f(vv[1]);
        a2 += gv * bf2f(vv[2]); a3 += gv * bf2f(vv[3]);
    }
    atomicAdd(wout + b * D_ + d + 0, a0);
    atomicAdd(wout + b * D_ + d + 1, a1);
    atomicAdd(wout + b * D_ + d + 2, a2);
    atomicAdd(wout + b * D_ + d + 3, a3);
}

// -------------------------- focal = relu(weighted@Wp1+bp1)@Wp2+bp2  (fp32)
__global__ __launch_bounds__(256)
void focal_kernel(const float* __restrict__ weighted, const float* __restrict__ Wp1,
                  const float* __restrict__ bp1, const float* __restrict__ Wp2,
                  const float* __restrict__ bp2, float* __restrict__ out)
{
    const int b = blockIdx.x, t = threadIdx.x;
    __shared__ float wsh[1024];
    __shared__ float hsh[512];
    for (int i = t; i < 1024; i += 256) wsh[i] = weighted[b * 1024 + i];
    __syncthreads();
    for (int j = t; j < 512; j += 256) {
        float a = bp1[j];
        for (int d2 = 0; d2 < 1024; ++d2) a += wsh[d2] * Wp1[d2 * 512 + j];
        hsh[j] = fmaxf(a, 0.f);
    }
    __syncthreads();
    for (int o = t; o < 128; o += 256) {
        float a = bp2[o];
        for (int j = 0; j < 512; ++j) a += hsh[j] * Wp2[j * 128 + o];
        out[b * 128 + o] = a;
    }
}

// ---------------------------------------------------------------- launcher
extern "C" void kernel_launch(void* const* d_in, const int* in_sizes, int n_in,
                              void* d_out, int out_size, void* d_ws, size_t ws_size,
                              hipStream_t stream)
{
    const float* patch     = (const float*)d_in[0];
    const float* curiosity = (const float*)d_in[1];
    const float* Wq  = (const float*)d_in[2];
    const float* bq  = (const float*)d_in[3];
    const float* Wk  = (const float*)d_in[4];
    const float* bk  = (const float*)d_in[5];
    const float* Wv  = (const float*)d_in[6];
    const float* bv  = (const float*)d_in[7];
    const float* Wc1 = (const float*)d_in[8];
    const float* bc1 = (const float*)d_in[9];
    const float* Wc2 = (const float*)d_in[10];
    const float* bc2 = (const float*)d_in[11];
    const float* Wp1 = (const float*)d_in[12];
    const float* bp1 = (const float*)d_in[13];
    const float* Wp2 = (const float*)d_in[14];
    const float* bp2 = (const float*)d_in[15];
    const float* aw  = (const float*)d_in[16];
    float* out = (float*)d_out;

    char* ws = (char*)d_ws;
    size_t off = 0;
    auto alloc = [&](size_t bytes) -> char* {
        char* p = ws + off;
        off += (bytes + 255) & ~(size_t)255;
        return p;
    };
    float*  pos  = (float*) alloc((size_t)N_ * D_ * 4);
    __bf16* X    = (__bf16*)alloc((size_t)B_ * NP * D_ * 2);
    __bf16* WqT  = (__bf16*)alloc((size_t)D_ * D_ * 2);
    __bf16* WkT  = (__bf16*)alloc((size_t)D_ * D_ * 2);
    __bf16* WvT  = (__bf16*)alloc((size_t)D_ * D_ * 2);
    __bf16* Q    = (__bf16*)alloc((size_t)B_ * NP * D_ * 2);
    __bf16* Kb   = (__bf16*)alloc((size_t)B_ * NP * D_ * 2);
    __bf16* V    = (__bf16*)alloc((size_t)B_ * NP * D_ * 2);
    __bf16* S    = (__bf16*)alloc((size_t)B_ * NP * NP * 2);   // scores -> attn in place
    float*  pa   = (float*) alloc((size_t)B_ * NP * 4);
    float*  faw  = (float*) alloc((size_t)B_ * NP * 4);
    float*  gbuf = (float*) alloc((size_t)B_ * NP * 4);
    float*  wsum = (float*) alloc((size_t)B_ * D_ * 4);

    (void)hipMemsetAsync(pa,   0, (size_t)B_ * NP * 4, stream);
    (void)hipMemsetAsync(gbuf, 0, (size_t)B_ * NP * 4, stream);
    (void)hipMemsetAsync(wsum, 0, (size_t)B_ * D_ * 4, stream);

    pos_kernel<<<(N_ * D_ + 255) / 256, 256, 0, stream>>>(pos);
    addpos_kernel<<<(int)((size_t)B_ * NP * D_ / 4 / 256), 256, 0, stream>>>(patch, pos, X);
    {
        dim3 g(16, 16, 3);
        wcast_kernel<<<g, 256, 0, stream>>>(Wq, Wk, Wv, WqT, WkT, WvT);
    }
    {
        dim3 g(D_ / 128, (B_ * NP) / 128, 1);
        gemm_tn<1><<<g, 256, 0, stream>>>(X, WqT, Q,  bq, B_ * NP, D_, D_, 1.f, 0, 0, 0);
        gemm_tn<1><<<g, 256, 0, stream>>>(X, WkT, Kb, bk, B_ * NP, D_, D_, 1.f, 0, 0, 0);
        gemm_tn<1><<<g, 256, 0, stream>>>(X, WvT, V,  bv, B_ * NP, D_, D_, 1.f, 0, 0, 0);
    }
    {
        dim3 g(NP / 128, NP / 128, B_);
        // scale = 1/sqrt(128)
        gemm_tn<0><<<g, 256, 0, stream>>>(Q, Kb, S, nullptr, NP, NP, D_,
                                          0.08838834764831845f,
                                          (long)NP * D_, (long)NP * D_, (long)NP * NP);
    }
    {
        dim3 g(N_, B_);
        softmax_kernel<<<g, 256, 0, stream>>>(S);
    }
    {
        dim3 g(6, B_, 8);
        colsum_kernel<0><<<g, 256, 0, stream>>>(S, nullptr, pa);
    }
    fa_kernel<<<B_, 256, 0, stream>>>(pa, curiosity, Wc1, bc1, Wc2, bc2, aw,
                                      faw, out + B_ * 128);
    {
        dim3 g(6, B_, 8);
        colsum_kernel<1><<<g, 256, 0, stream>>>(S, faw, gbuf);
    }
    {
        dim3 g(16, B_);
        weighted_kernel<<<g, 256, 0, stream>>>(gbuf, V, wsum);
    }
    focal_kernel<<<B_, 256, 0, stream>>>(wsum, Wp1, bp1, Wp2, bp2, out);
}

// Round 2
// 536.995 us; speedup vs baseline: 1.1911x; 1.1911x over previous
//
#include <hip/hip_runtime.h>
#include <hip/hip_bf16.h>
#include <cstdint>

#define B_   16
#define N_   1369
#define NP   1536
#define D_   1024
#define NQKV 3072

typedef __bf16 bf16x8_t __attribute__((ext_vector_type(8)));
typedef __bf16 bf16x4_t __attribute__((ext_vector_type(4)));
typedef float  f32x4_t  __attribute__((ext_vector_type(4)));

__device__ __forceinline__ float  bf2f(__bf16 x) { return (float)x; }
__device__ __forceinline__ __bf16 f2bf(float x)  { return (__bf16)x; }

#define GLOAD_LDS16(g, l) __builtin_amdgcn_global_load_lds( \
    (const __attribute__((address_space(1))) void*)(g),     \
    (__attribute__((address_space(3))) void*)(l), 16, 0, 0)

// ---------------------------------------------------------------- pos table
__global__ __launch_bounds__(256)
void pos_kernel(float* __restrict__ pos)
{
    const int idx = blockIdx.x * 256 + threadIdx.x;
    if (idx >= N_ * D_) return;
    const int n = idx >> 10, f = idx & 1023;
    const int row = n / 37, col = n - row * 37;
    const float base = (f < 512) ? (float)row : (float)col;
    const int  t2   = (f & 511) >> 1;
    const float dv  = __expf(-0.03597789207803197f * (float)t2);
    const float ang = base * dv;
    pos[idx] = (f & 1) ? cosf(ang) : sinf(ang);
}

// ----------------------------------------------- x = patch + pos, cast bf16
__global__ __launch_bounds__(256)
void addpos_kernel(const float* __restrict__ patch, const float* __restrict__ pos,
                   __bf16* __restrict__ X)
{
    const long tid = (long)blockIdx.x * 256 + threadIdx.x;
    const long e   = tid * 4;                 // element index in [B,NP,D]
    const int  f   = (int)(e & 1023);
    const long nb  = e >> 10;                 // b*NP + n
    const int  n   = (int)(nb % NP);
    const long b   = nb / NP;
    bf16x4_t o;
    if (n < N_) {
        const float4 p = *(const float4*)(patch + ((b * N_ + n) << 10) + f);
        const float4 q = *(const float4*)(pos + ((long)n << 10) + f);
        o[0] = f2bf(p.x + q.x); o[1] = f2bf(p.y + q.y);
        o[2] = f2bf(p.z + q.z); o[3] = f2bf(p.w + q.w);
    } else {
        o[0] = o[1] = o[2] = o[3] = f2bf(0.f);  // zero pad rows
    }
    *(bf16x4_t*)(X + e) = o;
}

// ------------------------------------ W[i][o] -> WT[o][i] bf16 (3 matrices)
__global__ __launch_bounds__(256)
void wcast_kernel(const float* __restrict__ W0, const float* __restrict__ W1,
                  const float* __restrict__ W2,
                  __bf16* __restrict__ T0, __bf16* __restrict__ T1, __bf16* __restrict__ T2)
{
    const float* W = blockIdx.z == 0 ? W0 : (blockIdx.z == 1 ? W1 : W2);
    __bf16*      T = blockIdx.z == 0 ? T0 : (blockIdx.z == 1 ? T1 : T2);
    __shared__ float tile[64][65];
    const int o0 = blockIdx.x * 64, i0 = blockIdx.y * 64;
    const int t = threadIdx.x;
    const int tr = t >> 4, tc = (t & 15) * 4;
    #pragma unroll
    for (int rr = 0; rr < 64; rr += 16) {
        float4 v = *(const float4*)(W + (long)(i0 + rr + tr) * 1024 + o0 + tc);
        tile[rr + tr][tc + 0] = v.x; tile[rr + tr][tc + 1] = v.y;
        tile[rr + tr][tc + 2] = v.z; tile[rr + tr][tc + 3] = v.w;
    }
    __syncthreads();
    #pragma unroll
    for (int rr = 0; rr < 64; rr += 16) {
        bf16x4_t o;
        o[0] = f2bf(tile[tc + 0][rr + tr]); o[1] = f2bf(tile[tc + 1][rr + tr]);
        o[2] = f2bf(tile[tc + 2][rr + tr]); o[3] = f2bf(tile[tc + 3][rr + tr]);
        *(bf16x4_t*)(T + (long)(o0 + rr + tr) * 1024 + i0 + tc) = o;
    }
}

// ---------------------------------------------- bias concat [bq|bk|bv] 3072
__global__ __launch_bounds__(256)
void bcat_kernel(const float* __restrict__ bq, const float* __restrict__ bk,
                 const float* __restrict__ bv, float* __restrict__ bcat)
{
    const int i = blockIdx.x * 256 + threadIdx.x;
    if (i >= NQKV) return;
    const int p = i >> 10, j = i & 1023;
    bcat[i] = p == 0 ? bq[j] : (p == 1 ? bk[j] : bv[j]);
}

// ------------------------------------------------------- 256^2 8-phase GEMM
// C[m,n] = scale*sum_k A[m,k]*Bt[n,k] (+bias[n]); bf16 in, fp32 acc, bf16 out.
// BM=BN=256, BK=64, 512 thr (8 waves 2x4), LDS 128 KiB (2 dbuf x (A 32K+B 32K)),
// st_16x32 swizzle (inverse-swizzled global src + swizzled ds_read),
// counted vmcnt(4) once per K-tile, raw s_barrier, setprio around MFMA.
template<int HAS_BIAS>
__global__ __launch_bounds__(512, 2)
void gemm256(const __bf16* __restrict__ A, const __bf16* __restrict__ Bt,
             __bf16* __restrict__ C, const float* __restrict__ bias,
             int lda, int ldb, int ldc, int Kd, float scale,
             long sA, long sB, long sC, int tilesN, int tilesPerBatch, int cpx)
{
    __shared__ __bf16 lds[65536];   // 128 KiB
    const int bid = blockIdx.x;
    const int vt  = (bid & 7) * cpx + (bid >> 3);      // XCD-bijective (nwg%8==0)
    const int bz  = vt / tilesPerBatch;
    const int rem = vt - bz * tilesPerBatch;
    const int ty  = rem / tilesN;
    const int tx  = rem - ty * tilesN;
    A  += (long)bz * sA;  Bt += (long)bz * sB;  C += (long)bz * sC;
    const int m0 = ty * 256, n0 = tx * 256;

    const int t  = threadIdx.x;
    const int w  = t >> 6, l = t & 63;
    const int wr = w >> 2, wc = w & 3;         // 2 x 4 wave grid
    const int lr = l & 15, lh = l >> 4;

    // swizzled ds_read lane offset (elems): row lr, k-slice lh within 32-k half
    const int laneF  = (lr * 64 + ((lh * 16) ^ (((lr >> 3) & 1) << 5))) >> 1;
    // staging source mapping (inverse swizzle): lane l covers row rstage, k kstage..+8
    const int rstage = w * 16 + (l >> 2);
    const int kstage = ((l & 3) * 8) ^ (((l >> 5) & 1) << 4);

    const __bf16* Ag = A  + (long)(m0 + rstage) * lda + kstage;
    const __bf16* Bg = Bt + (long)(n0 + rstage) * ldb + kstage;
    __bf16* dA = lds + (w * 2) * 512;           // + buf*32768 + half*8192
    __bf16* dB = lds + 16384 + (w * 2) * 512;

#define SA_(buf, half, kt) do {                                       \
    const __bf16* g_ = Ag + (long)(half) * 128 * lda + (kt) * 64;     \
    __bf16* d_ = dA + (buf) * 32768 + (half) * 8192;                  \
    GLOAD_LDS16(g_, d_); GLOAD_LDS16(g_ + 32, d_ + 512); } while (0)
#define SB_(buf, half, kt) do {                                       \
    const __bf16* g_ = Bg + (long)(half) * 128 * ldb + (kt) * 64;     \
    __bf16* d_ = dB + (buf) * 32768 + (half) * 8192;                  \
    GLOAD_LDS16(g_, d_); GLOAD_LDS16(g_ + 32, d_ + 512); } while (0)

    f32x4_t acc[8][4] = {};
    bf16x8_t bfr[4][2];

#define BREADS_() do { const __bf16* bp_ = lds + cbB + laneF;                              \
    bfr[0][0] = *(const bf16x8_t*)(bp_);        bfr[0][1] = *(const bf16x8_t*)(bp_ + 512); \
    bfr[1][0] = *(const bf16x8_t*)(bp_ + 1024); bfr[1][1] = *(const bf16x8_t*)(bp_ + 1536);\
    bfr[2][0] = *(const bf16x8_t*)(bp_ + 2048); bfr[2][1] = *(const bf16x8_t*)(bp_ + 2560);\
    bfr[3][0] = *(const bf16x8_t*)(bp_ + 3072); bfr[3][1] = *(const bf16x8_t*)(bp_ + 3584);} while (0)

#define PHASE_(p, P0R, STG, VMW) do {                                                  \
    const __bf16* ap_ = lds + cbase + wr * 8192 + (p) * 2048 + laneF;                  \
    bf16x8_t a00 = *(const bf16x8_t*)(ap_);                                            \
    bf16x8_t a01 = *(const bf16x8_t*)(ap_ + 512);                                      \
    bf16x8_t a10 = *(const bf16x8_t*)(ap_ + 1024);                                     \
    bf16x8_t a11 = *(const bf16x8_t*)(ap_ + 1536);                                     \
    P0R;                                                                               \
    STG;                                                                               \
    __builtin_amdgcn_s_barrier();                                                      \
    asm volatile("s_waitcnt lgkmcnt(0)" ::: "memory");                                 \
    __builtin_amdgcn_sched_barrier(0);                                                 \
    __builtin_amdgcn_s_setprio(1);                                                     \
    _Pragma("unroll") for (int nn = 0; nn < 4; ++nn)                                   \
      acc[(p)*2+0][nn] = __builtin_amdgcn_mfma_f32_16x16x32_bf16(a00, bfr[nn][0], acc[(p)*2+0][nn], 0, 0, 0); \
    _Pragma("unroll") for (int nn = 0; nn < 4; ++nn)                                   \
      acc[(p)*2+1][nn] = __builtin_amdgcn_mfma_f32_16x16x32_bf16(a10, bfr[nn][0], acc[(p)*2+1][nn], 0, 0, 0); \
    _Pragma("unroll") for (int nn = 0; nn < 4; ++nn)                                   \
      acc[(p)*2+0][nn] = __builtin_amdgcn_mfma_f32_16x16x32_bf16(a01, bfr[nn][1], acc[(p)*2+0][nn], 0, 0, 0); \
    _Pragma("unroll") for (int nn = 0; nn < 4; ++nn)                                   \
      acc[(p)*2+1][nn] = __builtin_amdgcn_mfma_f32_16x16x32_bf16(a11, bfr[nn][1], acc[(p)*2+1][nn], 0, 0, 0); \
    __builtin_amdgcn_s_setprio(0);                                                     \
    VMW;                                                                               \
    __builtin_amdgcn_s_barrier();                                                      \
  } while (0)

    const int NT = Kd >> 6;
    // prologue: tile0 fully + tile1 B halves in flight
    SA_(0, 0, 0); SA_(0, 1, 0); SB_(0, 0, 0); SB_(0, 1, 0);
    SB_(1, 0, 1); SB_(1, 1, 1);
    asm volatile("s_waitcnt vmcnt(4)" ::: "memory");
    __builtin_amdgcn_s_barrier();

    for (int tk = 0; tk < NT; ++tk) {
        const int c  = tk & 1, o = c ^ 1;
        const int t1 = (tk + 1 < NT) ? tk + 1 : NT - 1;   // clamped dummy at tail
        const int t2 = (tk + 2 < NT) ? tk + 2 : NT - 1;
        const int cbase = c * 32768;
        const int cbB   = cbase + 16384 + wc * 4096;
        PHASE_(0, BREADS_(), SA_(o, 0, t1), ((void)0));
        PHASE_(1, ((void)0), SA_(o, 1, t1), ((void)0));
        PHASE_(2, ((void)0), SB_(c, 0, t2), ((void)0));
        PHASE_(3, ((void)0), SB_(c, 1, t2),
               asm volatile("s_waitcnt vmcnt(4)" ::: "memory"));
    }

    // epilogue: C/D layout col=lane&15, row=(lane>>4)*4+reg
    #pragma unroll
    for (int mi = 0; mi < 8; ++mi) {
        const int row = m0 + wr * 128 + mi * 16 + lh * 4;
        #pragma unroll
        for (int nn = 0; nn < 4; ++nn) {
            const int col = n0 + wc * 64 + nn * 16 + lr;
            const float bb = HAS_BIAS ? bias[col] : 0.0f;
            #pragma unroll
            for (int q = 0; q < 4; ++q)
                C[(long)(row + q) * ldc + col] = f2bf(acc[mi][nn][q] * scale + bb);
        }
    }
#undef SA_
#undef SB_
#undef BREADS_
#undef PHASE_
}

// ------------------------------------------------- row softmax, in place
__global__ __launch_bounds__(256)
void softmax_kernel(__bf16* __restrict__ S)
{
    const int q = blockIdx.x, b = blockIdx.y;
    __bf16* row = S + ((long)b * NP + q) * NP;
    const int t = threadIdx.x;
    float v[6];
    float m = -1e30f;
    #pragma unroll
    for (int i = 0; i < 6; ++i) {
        const int k = t + i * 256;
        float x = -1e30f;
        if (k < N_) x = bf2f(row[k]);
        v[i] = x;
        m = fmaxf(m, x);
    }
    __shared__ float red[8];
    #pragma unroll
    for (int o = 32; o; o >>= 1) m = fmaxf(m, __shfl_xor(m, o));
    if (!(t & 63)) red[t >> 6] = m;
    __syncthreads();
    m = fmaxf(fmaxf(red[0], red[1]), fmaxf(red[2], red[3]));
    float s = 0.f;
    #pragma unroll
    for (int i = 0; i < 6; ++i) {
        const int k = t + i * 256;
        if (k < N_) { const float e = __expf(v[i] - m); v[i] = e; s += e; }
    }
    #pragma unroll
    for (int o = 32; o; o >>= 1) s += __shfl_xor(s, o);
    if (!(t & 63)) red[4 + (t >> 6)] = s;
    __syncthreads();
    s = red[4] + red[5] + red[6] + red[7];
    const float inv = 1.f / s;
    #pragma unroll
    for (int i = 0; i < 6; ++i) {
        const int k = t + i * 256;
        if (k < N_)      row[k] = f2bf(v[i] * inv);
        else             row[k] = f2bf(0.f);
    }
}

// --------------------- weighted column sums over attn (q-chunked + atomic)
template<int WEIGHTED>
__global__ __launch_bounds__(256)
void colsum_kernel(const __bf16* __restrict__ attn, const float* __restrict__ wv,
                   float* __restrict__ out)
{
    const int k = blockIdx.x * 256 + threadIdx.x;
    const int b = blockIdx.y;
    const int q0 = blockIdx.z * 172;
    const int q1 = (q0 + 172 < N_) ? q0 + 172 : N_;
    if (k >= N_) return;
    const __bf16* base = attn + (long)b * NP * NP + k;
    float s = 0.f;
    for (int q = q0; q < q1; ++q) {
        float a = bf2f(base[(long)q * NP]);
        if (WEIGHTED) a *= wv[b * NP + q];
        s += a;
    }
    atomicAdd(out + b * NP + k, s);
}

// ------------------- pa -> normalize -> curiosity modulation -> fa (output)
// var(pa) dominated by center-bias variance (~5e-3 >> 1e-6): branch 1 only.
__global__ __launch_bounds__(256)
void fa_kernel(const float* __restrict__ pa_raw, const float* __restrict__ curiosity,
               const float* __restrict__ Wc1, const float* __restrict__ bc1,
               const float* __restrict__ Wc2, const float* __restrict__ bc2,
               const float* __restrict__ aw_p,
               float* __restrict__ fa_ws, float* __restrict__ out_fa)
{
    const int b = blockIdx.x, t = threadIdx.x;
    __shared__ float hsh[64];
    __shared__ float red[8];
    __shared__ float cwsh;
    if (t < 64) hsh[t] = fmaxf(0.f, curiosity[b] * Wc1[t] + bc1[t]);
    __syncthreads();
    if (t < 8) {
        float a = bc2[t];
        for (int j = 0; j < 64; ++j) a += hsh[j] * Wc2[j * 8 + t];
        red[t] = 1.f / (1.f + __expf(-a));
    }
    __syncthreads();
    if (t == 0) {
        float cw = 0.f;
        for (int i = 0; i < 8; ++i) cw += red[i];
        cwsh = cw * 0.125f;
    }
    __syncthreads();
    const float aw   = aw_p[0];
    const float modf = 1.f + aw * cwsh;
    const float sig  = 37.f / 6.f;
    const float inv2s2 = 1.f / (2.f * sig * sig);
    float pv[6];
    float s1 = 0.f;
    #pragma unroll
    for (int i = 0; i < 6; ++i) {
        const int k = t + i * 256;
        float p = 0.f;
        if (k < N_) {
            const int y = k / 37, x = k - y * 37;
            const float d2 = (float)((x - 18) * (x - 18) + (y - 18) * (y - 18));
            const float cb = 0.3f * __expf(-d2 * inv2s2);
            p = pa_raw[b * NP + k] * (1.f / 1369.f) + cb;
        }
        pv[i] = p; s1 += p;
    }
    #pragma unroll
    for (int o = 32; o; o >>= 1) s1 += __shfl_xor(s1, o);
    __syncthreads();
    if (!(t & 63)) red[t >> 6] = s1;
    __syncthreads();
    s1 = red[0] + red[1] + red[2] + red[3];
    const float inv1 = 1.f / (s1 + 1e-8f);
    float s2 = 0.f;
    #pragma unroll
    for (int i = 0; i < 6; ++i) {
        const int k = t + i * 256;
        if (k < N_) {
            const float f = fmaxf(pv[i] * inv1 * modf, 1e-8f);
            pv[i] = f; s2 += f;
        }
    }
    #pragma unroll
    for (int o = 32; o; o >>= 1) s2 += __shfl_xor(s2, o);
    if (!(t & 63)) red[4 + (t >> 6)] = s2;
    __syncthreads();
    s2 = red[4] + red[5] + red[6] + red[7];
    const float inv2 = 1.f / (s2 + 1e-8f);
    #pragma unroll
    for (int i = 0; i < 6; ++i) {
        const int k = t + i * 256;
        if (k < N_) {
            const float f = pv[i] * inv2;
            fa_ws[b * NP + k]  = f;
            out_fa[b * N_ + k] = f;
        }
    }
}

// ------------------------------------- weighted[b,d] = sum_k g[b,k]*V[b,k,d]
__global__ __launch_bounds__(256)
void weighted_kernel(const float* __restrict__ g, const __bf16* __restrict__ V,
                     int ldv, float* __restrict__ wout)
{
    const int b  = blockIdx.y;
    const int k0 = blockIdx.x * 86;
    const int k1 = (k0 + 86 < N_) ? k0 + 86 : N_;
    const int d  = threadIdx.x * 4;
    float a0 = 0, a1 = 0, a2 = 0, a3 = 0;
    const __bf16* vb = V + (long)b * NP * ldv + d;
    for (int k = k0; k < k1; ++k) {
        const float gv = g[b * NP + k];
        bf16x4_t vv = *(const bf16x4_t*)(vb + (long)k * ldv);
        a0 += gv * bf2f(vv[0]); a1 += gv * bf2f(vv[1]);
        a2 += gv * bf2f(vv[2]); a3 += gv * bf2f(vv[3]);
    }
    atomicAdd(wout + b * D_ + d + 0, a0);
    atomicAdd(wout + b * D_ + d + 1, a1);
    atomicAdd(wout + b * D_ + d + 2, a2);
    atomicAdd(wout + b * D_ + d + 3, a3);
}

// -------------------------- focal = relu(weighted@Wp1+bp1)@Wp2+bp2  (fp32)
__global__ __launch_bounds__(256)
void focal_kernel(const float* __restrict__ weighted, const float* __restrict__ Wp1,
                  const float* __restrict__ bp1, const float* __restrict__ Wp2,
                  const float* __restrict__ bp2, float* __restrict__ out)
{
    const int b = blockIdx.x, t = threadIdx.x;
    __shared__ float wsh[1024];
    __shared__ float hsh[512];
    for (int i = t; i < 1024; i += 256) wsh[i] = weighted[b * 1024 + i];
    __syncthreads();
    for (int j = t; j < 512; j += 256) {
        float a = bp1[j];
        for (int d2 = 0; d2 < 1024; ++d2) a += wsh[d2] * Wp1[d2 * 512 + j];
        hsh[j] = fmaxf(a, 0.f);
    }
    __syncthreads();
    for (int o = t; o < 128; o += 256) {
        float a = bp2[o];
        for (int j = 0; j < 512; ++j) a += hsh[j] * Wp2[j * 128 + o];
        out[b * 128 + o] = a;
    }
}

// ---------------------------------------------------------------- launcher
extern "C" void kernel_launch(void* const* d_in, const int* in_sizes, int n_in,
                              void* d_out, int out_size, void* d_ws, size_t ws_size,
                              hipStream_t stream)
{
    const float* patch     = (const float*)d_in[0];
    const float* curiosity = (const float*)d_in[1];
    const float* Wq  = (const float*)d_in[2];
    const float* bq  = (const float*)d_in[3];
    const float* Wk  = (const float*)d_in[4];
    const float* bk  = (const float*)d_in[5];
    const float* Wv  = (const float*)d_in[6];
    const float* bv  = (const float*)d_in[7];
    const float* Wc1 = (const float*)d_in[8];
    const float* bc1 = (const float*)d_in[9];
    const float* Wc2 = (const float*)d_in[10];
    const float* bc2 = (const float*)d_in[11];
    const float* Wp1 = (const float*)d_in[12];
    const float* bp1 = (const float*)d_in[13];
    const float* Wp2 = (const float*)d_in[14];
    const float* bp2 = (const float*)d_in[15];
    const float* aw  = (const float*)d_in[16];
    float* out = (float*)d_out;

    char* ws = (char*)d_ws;
    size_t off = 0;
    auto alloc = [&](size_t bytes) -> char* {
        char* p = ws + off;
        off += (bytes + 255) & ~(size_t)255;
        return p;
    };
    // region 0: {pos, X, WT} -- later aliased by S (all fully rewritten each call)
    float*  pos  = (float*) alloc((size_t)N_ * D_ * 4);                 // 5.6 MB
    __bf16* X    = (__bf16*)alloc((size_t)B_ * NP * D_ * 2);            // 50.3 MB
    __bf16* WT   = (__bf16*)alloc((size_t)3 * D_ * D_ * 2);             // 6.3 MB
    const size_t S_BYTES = (size_t)B_ * NP * NP * 2;                    // 75.5 MB
    if (off < S_BYTES) off = S_BYTES;
    __bf16* S    = (__bf16*)ws;                                         // alias region 0
    __bf16* QKV  = (__bf16*)alloc((size_t)B_ * NP * NQKV * 2);          // 151 MB
    float*  pa   = (float*) alloc((size_t)B_ * NP * 4);
    float*  faw  = (float*) alloc((size_t)B_ * NP * 4);
    float*  gbuf = (float*) alloc((size_t)B_ * NP * 4);
    float*  wsum = (float*) alloc((size_t)B_ * D_ * 4);
    float*  bcat = (float*) alloc((size_t)NQKV * 4);

    (void)hipMemsetAsync(pa,   0, (size_t)B_ * NP * 4, stream);
    (void)hipMemsetAsync(gbuf, 0, (size_t)B_ * NP * 4, stream);
    (void)hipMemsetAsync(wsum, 0, (size_t)B_ * D_ * 4, stream);

    pos_kernel<<<(N_ * D_ + 255) / 256, 256, 0, stream>>>(pos);
    addpos_kernel<<<(int)((size_t)B_ * NP * D_ / 4 / 256), 256, 0, stream>>>(patch, pos, X);
    {
        dim3 g(16, 16, 3);
        wcast_kernel<<<g, 256, 0, stream>>>(Wq, Wk, Wv,
                                            WT, WT + D_ * D_, WT + 2 * D_ * D_);
    }
    bcat_kernel<<<(NQKV + 255) / 256, 256, 0, stream>>>(bq, bk, bv, bcat);
    {
        // QKV projection: M=B*NP=24576(96), N=3072(12), K=1024 -> 1152 blocks
        const int nwg = 96 * 12;
        gemm256<1><<<nwg, 512, 0, stream>>>(X, WT, QKV, bcat,
                                            D_, D_, NQKV, D_, 1.0f,
                                            0, 0, 0, 12, nwg, nwg / 8);
    }
    {
        // scores: per batch M=N=1536(6x6), K=1024; 16 batches -> 576 blocks
        const int nwg = 36 * B_;
        gemm256<0><<<nwg, 512, 0, stream>>>(QKV, QKV + D_, S, nullptr,
                                            NQKV, NQKV, NP, D_,
                                            0.08838834764831845f,
                                            (long)NP * NQKV, (long)NP * NQKV,
                                            (long)NP * NP, 6, 36, nwg / 8);
    }
    {
        dim3 g(N_, B_);
        softmax_kernel<<<g, 256, 0, stream>>>(S);
    }
    {
        dim3 g(6, B_, 8);
        colsum_kernel<0><<<g, 256, 0, stream>>>(S, nullptr, pa);
    }
    fa_kernel<<<B_, 256, 0, stream>>>(pa, curiosity, Wc1, bc1, Wc2, bc2, aw,
                                      faw, out + B_ * 128);
    {
        dim3 g(6, B_, 8);
        colsum_kernel<1><<<g, 256, 0, stream>>>(S, faw, gbuf);
    }
    {
        dim3 g(16, B_);
        weighted_kernel<<<g, 256, 0, stream>>>(gbuf, QKV + 2 * D_, NQKV, wsum);
    }
    focal_kernel<<<B_, 256, 0, stream>>>(wsum, Wp1, bp1, Wp2, bp2, out);
}